// Round 1
// baseline (236.417 us; speedup 1.0000x reference)
//
#include <hip/hip_runtime.h>
#include <hip/hip_bf16.h>

// Problem: out = x @ W_eff^T + bias   (TOKENS=2048, N=4096, M=K=4096)
// W_eff = rownorm-rescaled Givens-rotated W; pairs are (2s,2s+1) adjacent.

#define GK 4096      // inner dim (M in reference)
#define GN 4096      // output cols (N rows of W)
#define GT 2048      // tokens

typedef __bf16 bf16x8 __attribute__((ext_vector_type(8)));
typedef float  f32x4  __attribute__((ext_vector_type(4)));

static __device__ __forceinline__ unsigned short f2bf(float f) {
    union { float f; unsigned int u; } v; v.f = f;
    unsigned int r = v.u + 0x7fffu + ((v.u >> 16) & 1u);   // RNE
    return (unsigned short)(r >> 16);
}
static __device__ __forceinline__ unsigned int pack2bf(float a, float b) {
    return (unsigned int)f2bf(a) | ((unsigned int)f2bf(b) << 16);
}

// ---------------- Kernel 1: build W_eff (bf16) ----------------
// One block per row pair s: rows i0=2s, i1=2s+1. 256 threads, 8 col-pairs each.
__global__ __launch_bounds__(256) void make_weff(
    const float* __restrict__ W, const float* __restrict__ thL,
    const float* __restrict__ thR, const float* __restrict__ ecd,
    unsigned short* __restrict__ Weff)
{
    const int s   = blockIdx.x;
    const int i0  = 2 * s, i1 = 2 * s + 1;
    const int tid = threadIdx.x;

    const float tl = thL[s];
    const float cL = cosf(tl), sL = sinf(tl);

    float b00[8], b01[8], b10[8], b11[8];
    float sw0 = 0.f, sw1 = 0.f, sb0 = 0.f, sb1 = 0.f;

    const float2* r0 = (const float2*)(W + (size_t)i0 * GK);
    const float2* r1 = (const float2*)(W + (size_t)i1 * GK);

#pragma unroll
    for (int k = 0; k < 8; k++) {
        const int p = tid + k * 256;           // col pair index 0..2047
        const float2 w0 = r0[p];
        const float2 w1 = r1[p];
        const float tr = thR[p];
        const float cR = cosf(tr), sR = sinf(tr);
        // left rotation (rows)
        const float a0x = cL * w0.x - sL * w1.x;
        const float a0y = cL * w0.y - sL * w1.y;
        const float a1x = sL * w0.x + cL * w1.x;
        const float a1y = sL * w0.y + cL * w1.y;
        // right rotation (cols)
        b00[k] = cR * a0x - sR * a0y;
        b01[k] = sR * a0x + cR * a0y;
        b10[k] = cR * a1x - sR * a1y;
        b11[k] = sR * a1x + cR * a1y;
        sw0 += w0.x * w0.x + w0.y * w0.y;
        sw1 += w1.x * w1.x + w1.y * w1.y;
        sb0 += b00[k] * b00[k] + b01[k] * b01[k];
        sb1 += b10[k] * b10[k] + b11[k] * b11[k];
    }

    // block reduction of the 4 sums
#pragma unroll
    for (int off = 32; off; off >>= 1) {
        sw0 += __shfl_down(sw0, off);
        sw1 += __shfl_down(sw1, off);
        sb0 += __shfl_down(sb0, off);
        sb1 += __shfl_down(sb1, off);
    }
    __shared__ float red[4][4];
    __shared__ float scales[2];
    const int wave = tid >> 6, lane = tid & 63;
    if (lane == 0) {
        red[0][wave] = sw0; red[1][wave] = sw1;
        red[2][wave] = sb0; red[3][wave] = sb1;
    }
    __syncthreads();
    if (tid == 0) {
        const float t0 = red[0][0] + red[0][1] + red[0][2] + red[0][3];
        const float t1 = red[1][0] + red[1][1] + red[1][2] + red[1][3];
        const float t2 = red[2][0] + red[2][1] + red[2][2] + red[2][3];
        const float t3 = red[3][0] + red[3][1] + red[3][2] + red[3][3];
        scales[0] = sqrtf(t0) * expf(ecd[i0]) / (sqrtf(t2) + 1e-8f);
        scales[1] = sqrtf(t1) * expf(ecd[i1]) / (sqrtf(t3) + 1e-8f);
    }
    __syncthreads();
    const float sc0 = scales[0], sc1 = scales[1];

    unsigned int* o0 = (unsigned int*)(Weff + (size_t)i0 * GK);
    unsigned int* o1 = (unsigned int*)(Weff + (size_t)i1 * GK);
#pragma unroll
    for (int k = 0; k < 8; k++) {
        const int p = tid + k * 256;
        o0[p] = pack2bf(b00[k] * sc0, b01[k] * sc0);
        o1[p] = pack2bf(b10[k] * sc1, b11[k] * sc1);
    }
}

// ---------------- Kernel 2: x f32 -> bf16 ----------------
__global__ __launch_bounds__(256) void cvt_x(
    const float4* __restrict__ X, unsigned long long* __restrict__ O, int n4)
{
    const int i = blockIdx.x * 256 + threadIdx.x;
    if (i < n4) {
        const float4 v = X[i];
        O[i] = (unsigned long long)f2bf(v.x)
             | ((unsigned long long)f2bf(v.y) << 16)
             | ((unsigned long long)f2bf(v.z) << 32)
             | ((unsigned long long)f2bf(v.w) << 48);
    }
}

// ---------------- Kernel 3: GEMM  out = Xbf @ Weff^T + bias ----------------
// m97 structure: 128x128 tile, BK=32, 4 waves in 2x2, 4x4 mfma_16x16x32_bf16
// per wave, global_load_lds width=16 staging, 2-barrier K-loop.
static __device__ __forceinline__ void glds16(const unsigned short* g, unsigned short* l) {
    __builtin_amdgcn_global_load_lds(
        (const __attribute__((address_space(1))) unsigned int*)g,
        (__attribute__((address_space(3))) unsigned int*)l, 16, 0, 0);
}

__global__ __launch_bounds__(256) void gemm_bt(
    const unsigned short* __restrict__ A,   // (GT, GK) bf16
    const unsigned short* __restrict__ B,   // (GN, GK) bf16
    const float* __restrict__ bias,
    float* __restrict__ C)                  // (GT, GN) f32
{
    constexpr int BM = 128, BN = 128, BK = 32;
    __shared__ unsigned short As[BM * BK];
    __shared__ unsigned short Bs[BN * BK];

    const int tid  = threadIdx.x;
    const int lane = tid & 63;
    const int wave = tid >> 6;
    const int quad = lane >> 4;
    const int l16  = lane & 15;
    const int wm   = wave >> 1;     // 0..1
    const int wn   = wave & 1;      // 0..1
    const int bm   = blockIdx.y * BM;
    const int bn   = blockIdx.x * BN;

    // staging: each wave stages 32 rows of A-tile and 32 rows of B-tile
    const int srow = wave * 32 + (lane >> 2);   // tile row
    const int scol = (lane & 3) * 8;            // k within BK, units of bf16
    const unsigned short* gA0 = A + (size_t)(bm + srow) * GK + scol;
    const unsigned short* gA1 = A + (size_t)(bm + srow + 16) * GK + scol;
    const unsigned short* gB0 = B + (size_t)(bn + srow) * GK + scol;
    const unsigned short* gB1 = B + (size_t)(bn + srow + 16) * GK + scol;
    unsigned short* lA0 = &As[srow * BK + scol];
    unsigned short* lA1 = &As[(srow + 16) * BK + scol];
    unsigned short* lB0 = &Bs[srow * BK + scol];
    unsigned short* lB1 = &Bs[(srow + 16) * BK + scol];

    f32x4 acc[4][4] = {};

    for (int k0 = 0; k0 < GK; k0 += BK) {
        __syncthreads();                 // LDS reuse guard
        glds16(gA0 + k0, lA0);
        glds16(gA1 + k0, lA1);
        glds16(gB0 + k0, lB0);
        glds16(gB1 + k0, lB1);
        __syncthreads();                 // drains vmcnt before reads

        bf16x8 aF[4], bF[4];
#pragma unroll
        for (int i = 0; i < 4; i++)
            aF[i] = *(const bf16x8*)&As[(wm * 64 + i * 16 + l16) * BK + quad * 8];
#pragma unroll
        for (int j = 0; j < 4; j++)
            bF[j] = *(const bf16x8*)&Bs[(wn * 64 + j * 16 + l16) * BK + quad * 8];
#pragma unroll
        for (int i = 0; i < 4; i++)
#pragma unroll
            for (int j = 0; j < 4; j++)
                acc[i][j] = __builtin_amdgcn_mfma_f32_16x16x32_bf16(
                    aF[i], bF[j], acc[i][j], 0, 0, 0);
    }

    // epilogue: C/D layout col=lane&15, row=quad*4+reg   (m89/m91 verified)
#pragma unroll
    for (int i = 0; i < 4; i++) {
        const int m = bm + wm * 64 + i * 16 + quad * 4;
#pragma unroll
        for (int j = 0; j < 4; j++) {
            const int n = bn + wn * 64 + j * 16 + l16;
            const float bv = bias[n];
#pragma unroll
            for (int r = 0; r < 4; r++)
                C[(size_t)(m + r) * GN + n] = acc[i][j][r] + bv;
        }
    }
}

extern "C" void kernel_launch(void* const* d_in, const int* in_sizes, int n_in,
                              void* d_out, int out_size, void* d_ws, size_t ws_size,
                              hipStream_t stream) {
    const float* x    = (const float*)d_in[0];
    const float* W    = (const float*)d_in[1];
    const float* bias = (const float*)d_in[2];
    const float* thL  = (const float*)d_in[3];
    const float* thR  = (const float*)d_in[4];
    const float* ecd  = (const float*)d_in[5];
    // pairs_L / pairs_R (d_in[6], d_in[7]) are fixed arange(N).reshape(S,2):
    // pair s = (2s, 2s+1) — exploited structurally above.

    unsigned short* Weff = (unsigned short*)d_ws;                               // 32 MB
    unsigned short* Xbf  = (unsigned short*)((char*)d_ws + (size_t)GN * GK * 2); // 16 MB
    float* out = (float*)d_out;

    make_weff<<<dim3(GN / 2), dim3(256), 0, stream>>>(W, thL, thR, ecd, Weff);
    cvt_x<<<dim3((GT * GK / 4) / 256), dim3(256), 0, stream>>>(
        (const float4*)x, (unsigned long long*)Xbf, GT * GK / 4);
    gemm_bt<<<dim3(GN / 128, GT / 128), dim3(256), 0, stream>>>(Xbf, Weff, bias, out);
}

// Round 2
// 230.108 us; speedup vs baseline: 1.0274x; 1.0274x over previous
//
#include <hip/hip_runtime.h>
#include <hip/hip_bf16.h>

// Problem: out = x @ W_eff^T + bias   (TOKENS=2048, N=4096, M=K=4096)
// W_eff = rownorm-rescaled Givens-rotated W; pairs are (2s,2s+1) adjacent,
// so row pair (2s,2s+1) and col pair (2t,2t+1) are closed 2x2 blocks.

#define GK 4096      // inner dim (M in reference)
#define GN 4096      // output cols (N rows of W)
#define GT 2048      // tokens

typedef __bf16 bf16x8 __attribute__((ext_vector_type(8)));
typedef float  f32x4  __attribute__((ext_vector_type(4)));

static __device__ __forceinline__ unsigned short f2bf(float f) {
    union { float f; unsigned int u; } v; v.f = f;
    unsigned int r = v.u + 0x7fffu + ((v.u >> 16) & 1u);   // RNE
    return (unsigned short)(r >> 16);
}
static __device__ __forceinline__ unsigned int pack2bf(float a, float b) {
    return (unsigned int)f2bf(a) | ((unsigned int)f2bf(b) << 16);
}

// ---------------- Fused prelude ----------------
// blocks [0, 2048): build W_eff row pair s (bf16), single pass over W.
// blocks [2048, 4096): convert a 32 KB slice of x to bf16.
// One dispatch, 4096 blocks = 16/CU, pure streaming.
__global__ __launch_bounds__(256) void prelude(
    const float* __restrict__ W, const float* __restrict__ thL,
    const float* __restrict__ thR, const float* __restrict__ ecd,
    const float* __restrict__ x,
    unsigned short* __restrict__ Weff, unsigned short* __restrict__ Xbf)
{
    const int tid = threadIdx.x;

    if (blockIdx.x >= 2048) {
        // ---- x f32 -> bf16: block handles 512 chunks of 8 floats ----
        const int cb = blockIdx.x - 2048;
        const size_t base = (size_t)cb * 512;             // 8-float chunk index
        const float4* X4 = (const float4*)x;
        uint4* O4 = (uint4*)Xbf;
#pragma unroll
        for (int k = 0; k < 2; k++) {
            const size_t m = base + tid + k * 256;        // chunk index
            const float4 a = X4[2 * m];
            const float4 b = X4[2 * m + 1];
            uint4 o;
            o.x = pack2bf(a.x, a.y);
            o.y = pack2bf(a.z, a.w);
            o.z = pack2bf(b.x, b.y);
            o.w = pack2bf(b.z, b.w);
            O4[m] = o;
        }
        return;
    }

    // ---- W_eff for row pair s ----
    const int s  = blockIdx.x;
    const int i0 = 2 * s, i1 = 2 * s + 1;

    const float tl = thL[s];
    const float cL = cosf(tl), sL = sinf(tl);

    // 4 iterations x float4 (2 col pairs) per row: 16 cols/thread/row
    float4 b0[4], b1[4];
    float sw0 = 0.f, sw1 = 0.f, sb0 = 0.f, sb1 = 0.f;

    const float4* r0 = (const float4*)(W + (size_t)i0 * GK);
    const float4* r1 = (const float4*)(W + (size_t)i1 * GK);
    const float2* tR = (const float2*)thR;                 // pair (2t, 2t+1)

#pragma unroll
    for (int k = 0; k < 4; k++) {
        const int c4 = tid + k * 256;       // float4 index: cols 4*c4 .. +3
        const float4 w0 = r0[c4];
        const float4 w1 = r1[c4];
        const float2 tr = tR[c4];           // thetas for col pairs 2*c4, 2*c4+1
        const float cR0 = cosf(tr.x), sR0 = sinf(tr.x);
        const float cR1 = cosf(tr.y), sR1 = sinf(tr.y);
        // left rotation (row mix)
        const float a0x = cL * w0.x - sL * w1.x;
        const float a0y = cL * w0.y - sL * w1.y;
        const float a0z = cL * w0.z - sL * w1.z;
        const float a0w = cL * w0.w - sL * w1.w;
        const float a1x = sL * w0.x + cL * w1.x;
        const float a1y = sL * w0.y + cL * w1.y;
        const float a1z = sL * w0.z + cL * w1.z;
        const float a1w = sL * w0.w + cL * w1.w;
        // right rotation (col mix within (x,y) and (z,w))
        b0[k].x = cR0 * a0x - sR0 * a0y;
        b0[k].y = sR0 * a0x + cR0 * a0y;
        b0[k].z = cR1 * a0z - sR1 * a0w;
        b0[k].w = sR1 * a0z + cR1 * a0w;
        b1[k].x = cR0 * a1x - sR0 * a1y;
        b1[k].y = sR0 * a1x + cR0 * a1y;
        b1[k].z = cR1 * a1z - sR1 * a1w;
        b1[k].w = sR1 * a1z + cR1 * a1w;
        sw0 += w0.x * w0.x + w0.y * w0.y + w0.z * w0.z + w0.w * w0.w;
        sw1 += w1.x * w1.x + w1.y * w1.y + w1.z * w1.z + w1.w * w1.w;
        sb0 += b0[k].x * b0[k].x + b0[k].y * b0[k].y + b0[k].z * b0[k].z + b0[k].w * b0[k].w;
        sb1 += b1[k].x * b1[k].x + b1[k].y * b1[k].y + b1[k].z * b1[k].z + b1[k].w * b1[k].w;
    }

    // block reduction of the 4 sums
#pragma unroll
    for (int off = 32; off; off >>= 1) {
        sw0 += __shfl_down(sw0, off);
        sw1 += __shfl_down(sw1, off);
        sb0 += __shfl_down(sb0, off);
        sb1 += __shfl_down(sb1, off);
    }
    __shared__ float red[4][4];
    __shared__ float scales[2];
    const int wave = tid >> 6, lane = tid & 63;
    if (lane == 0) {
        red[0][wave] = sw0; red[1][wave] = sw1;
        red[2][wave] = sb0; red[3][wave] = sb1;
    }
    __syncthreads();
    if (tid == 0) {
        const float t0 = red[0][0] + red[0][1] + red[0][2] + red[0][3];
        const float t1 = red[1][0] + red[1][1] + red[1][2] + red[1][3];
        const float t2 = red[2][0] + red[2][1] + red[2][2] + red[2][3];
        const float t3 = red[3][0] + red[3][1] + red[3][2] + red[3][3];
        scales[0] = sqrtf(t0) * expf(ecd[i0]) / (sqrtf(t2) + 1e-8f);
        scales[1] = sqrtf(t1) * expf(ecd[i1]) / (sqrtf(t3) + 1e-8f);
    }
    __syncthreads();
    const float sc0 = scales[0], sc1 = scales[1];

    uint2* o0 = (uint2*)(Weff + (size_t)i0 * GK);   // 4 bf16 = 8B per float4
    uint2* o1 = (uint2*)(Weff + (size_t)i1 * GK);
#pragma unroll
    for (int k = 0; k < 4; k++) {
        const int c4 = tid + k * 256;
        uint2 p0, p1;
        p0.x = pack2bf(b0[k].x * sc0, b0[k].y * sc0);
        p0.y = pack2bf(b0[k].z * sc0, b0[k].w * sc0);
        p1.x = pack2bf(b1[k].x * sc1, b1[k].y * sc1);
        p1.y = pack2bf(b1[k].z * sc1, b1[k].w * sc1);
        o0[c4] = p0;
        o1[c4] = p1;
    }
}

// ---------------- GEMM  out = Xbf @ Weff^T + bias ----------------
// m97 structure: 128x128 tile, BK=32, 4 waves in 2x2, 4x4 mfma_16x16x32_bf16
// per wave, global_load_lds width=16 staging, 2-barrier K-loop. (unchanged)
static __device__ __forceinline__ void glds16(const unsigned short* g, unsigned short* l) {
    __builtin_amdgcn_global_load_lds(
        (const __attribute__((address_space(1))) unsigned int*)g,
        (__attribute__((address_space(3))) unsigned int*)l, 16, 0, 0);
}

__global__ __launch_bounds__(256) void gemm_bt(
    const unsigned short* __restrict__ A,   // (GT, GK) bf16
    const unsigned short* __restrict__ B,   // (GN, GK) bf16
    const float* __restrict__ bias,
    float* __restrict__ C)                  // (GT, GN) f32
{
    constexpr int BM = 128, BN = 128, BK = 32;
    __shared__ unsigned short As[BM * BK];
    __shared__ unsigned short Bs[BN * BK];

    const int tid  = threadIdx.x;
    const int lane = tid & 63;
    const int wave = tid >> 6;
    const int quad = lane >> 4;
    const int l16  = lane & 15;
    const int wm   = wave >> 1;     // 0..1
    const int wn   = wave & 1;      // 0..1
    const int bm   = blockIdx.y * BM;
    const int bn   = blockIdx.x * BN;

    const int srow = wave * 32 + (lane >> 2);   // tile row
    const int scol = (lane & 3) * 8;            // k within BK, bf16 units
    const unsigned short* gA0 = A + (size_t)(bm + srow) * GK + scol;
    const unsigned short* gA1 = A + (size_t)(bm + srow + 16) * GK + scol;
    const unsigned short* gB0 = B + (size_t)(bn + srow) * GK + scol;
    const unsigned short* gB1 = B + (size_t)(bn + srow + 16) * GK + scol;
    unsigned short* lA0 = &As[srow * BK + scol];
    unsigned short* lA1 = &As[(srow + 16) * BK + scol];
    unsigned short* lB0 = &Bs[srow * BK + scol];
    unsigned short* lB1 = &Bs[(srow + 16) * BK + scol];

    f32x4 acc[4][4] = {};

    for (int k0 = 0; k0 < GK; k0 += BK) {
        __syncthreads();                 // LDS reuse guard
        glds16(gA0 + k0, lA0);
        glds16(gA1 + k0, lA1);
        glds16(gB0 + k0, lB0);
        glds16(gB1 + k0, lB1);
        __syncthreads();                 // drains vmcnt before reads

        bf16x8 aF[4], bF[4];
#pragma unroll
        for (int i = 0; i < 4; i++)
            aF[i] = *(const bf16x8*)&As[(wm * 64 + i * 16 + l16) * BK + quad * 8];
#pragma unroll
        for (int j = 0; j < 4; j++)
            bF[j] = *(const bf16x8*)&Bs[(wn * 64 + j * 16 + l16) * BK + quad * 8];
#pragma unroll
        for (int i = 0; i < 4; i++)
#pragma unroll
            for (int j = 0; j < 4; j++)
                acc[i][j] = __builtin_amdgcn_mfma_f32_16x16x32_bf16(
                    aF[i], bF[j], acc[i][j], 0, 0, 0);
    }

    // epilogue: C/D layout col=lane&15, row=quad*4+reg   (m89/m91 verified)
#pragma unroll
    for (int i = 0; i < 4; i++) {
        const int m = bm + wm * 64 + i * 16 + quad * 4;
#pragma unroll
        for (int j = 0; j < 4; j++) {
            const int n = bn + wn * 64 + j * 16 + l16;
            const float bv = bias[n];
#pragma unroll
            for (int r = 0; r < 4; r++)
                C[(size_t)(m + r) * GN + n] = acc[i][j][r] + bv;
        }
    }
}

extern "C" void kernel_launch(void* const* d_in, const int* in_sizes, int n_in,
                              void* d_out, int out_size, void* d_ws, size_t ws_size,
                              hipStream_t stream) {
    const float* x    = (const float*)d_in[0];
    const float* W    = (const float*)d_in[1];
    const float* bias = (const float*)d_in[2];
    const float* thL  = (const float*)d_in[3];
    const float* thR  = (const float*)d_in[4];
    const float* ecd  = (const float*)d_in[5];
    // pairs_L / pairs_R (d_in[6], d_in[7]) are fixed arange reshapes:
    // pair s = (2s, 2s+1) — exploited structurally above.

    unsigned short* Weff = (unsigned short*)d_ws;                                // 32 MB
    unsigned short* Xbf  = (unsigned short*)((char*)d_ws + (size_t)GN * GK * 2); // 16 MB
    float* out = (float*)d_out;

    prelude<<<dim3(4096), dim3(256), 0, stream>>>(W, thL, thR, ecd, x, Weff, Xbf);
    gemm_bt<<<dim3(GN / 128, GT / 128), dim3(256), 0, stream>>>(Xbf, Weff, bias, out);
}

// Round 3
// 226.544 us; speedup vs baseline: 1.0436x; 1.0157x over previous
//
#include <hip/hip_runtime.h>
#include <hip/hip_bf16.h>

// Problem: out = x @ W_eff^T + bias   (TOKENS=2048, N=4096, M=K=4096)
// W_eff = rownorm-rescaled Givens-rotated W; pairs are (2s,2s+1) adjacent,
// so row pair (2s,2s+1) and col pair (2t,2t+1) are closed 2x2 blocks.
//
// Norm identity: right rotations are orthogonal on the column space ->
// preserve each row's norm. So ||Wp row|| needs only ||w0||^2, ||w1||^2,
// <w0,w1> (3 reduced scalars), not the rotated data.

#define GK 4096      // inner dim (M in reference)
#define GN 4096      // output cols (N rows of W)
#define GT 2048      // tokens
#define NPAIR 2048   // S

typedef __bf16 bf16x8 __attribute__((ext_vector_type(8)));
typedef float  f32x4  __attribute__((ext_vector_type(4)));

static __device__ __forceinline__ unsigned short f2bf(float f) {
    union { float f; unsigned int u; } v; v.f = f;
    unsigned int r = v.u + 0x7fffu + ((v.u >> 16) & 1u);   // RNE
    return (unsigned short)(r >> 16);
}
static __device__ __forceinline__ unsigned int pack2bf(float a, float b) {
    return (unsigned int)f2bf(a) | ((unsigned int)f2bf(b) << 16);
}

// ---------------- Kernel 0: precompute (cos,sin) of theta_R ----------------
// 2048 sincos chip-wide instead of 2048 per block (4096x redundancy removed).
__global__ __launch_bounds__(256) void sincos_pre(
    const float* __restrict__ thR, float2* __restrict__ csR)
{
    const int i = blockIdx.x * 256 + threadIdx.x;
    if (i < NPAIR) {
        const float t = thR[i];
        csR[i] = make_float2(cosf(t), sinf(t));
    }
}

// ---------------- Fused prelude ----------------
// blocks [0, 2048): build W_eff row pair s (bf16), single pass over W.
// blocks [2048, 4096): convert a 32 KB slice of x to bf16.
__global__ __launch_bounds__(256) void prelude(
    const float* __restrict__ W, const float* __restrict__ thL,
    const float2* __restrict__ csR, const float* __restrict__ ecd,
    const float* __restrict__ x,
    unsigned short* __restrict__ Weff, unsigned short* __restrict__ Xbf)
{
    const int tid = threadIdx.x;

    if (blockIdx.x >= 2048) {
        // ---- x f32 -> bf16 ----
        const int cb = blockIdx.x - 2048;
        const size_t base = (size_t)cb * 512;             // 8-float chunk index
        const float4* X4 = (const float4*)x;
        uint4* O4 = (uint4*)Xbf;
#pragma unroll
        for (int k = 0; k < 2; k++) {
            const size_t m = base + tid + k * 256;
            const float4 a = X4[2 * m];
            const float4 b = X4[2 * m + 1];
            uint4 o;
            o.x = pack2bf(a.x, a.y);
            o.y = pack2bf(a.z, a.w);
            o.z = pack2bf(b.x, b.y);
            o.w = pack2bf(b.z, b.w);
            O4[m] = o;
        }
        return;
    }

    // ---- W_eff for row pair s ----
    const int s  = blockIdx.x;
    const int i0 = 2 * s, i1 = 2 * s + 1;

    const float tl = thL[s];
    const float cL = cosf(tl), sL = sinf(tl);   // 2 ocml calls/block total

    float4 b0[4], b1[4];                        // rotated rows (held)
    float s00 = 0.f, s11 = 0.f, s01 = 0.f;      // ||w0||^2, ||w1||^2, <w0,w1>

    const float4* r0  = (const float4*)(W + (size_t)i0 * GK);
    const float4* r1  = (const float4*)(W + (size_t)i1 * GK);
    const float4* CS4 = (const float4*)csR;     // (c0,s0,c1,s1) per float4 of cols

#pragma unroll
    for (int k = 0; k < 4; k++) {
        const int c4 = tid + k * 256;           // float4 index: cols 4*c4 .. +3
        const float4 w0 = r0[c4];
        const float4 w1 = r1[c4];
        const float4 cs = CS4[c4];              // cR0,sR0,cR1,sR1 (16 KB, L2-hot)
        s00 += w0.x * w0.x + w0.y * w0.y + w0.z * w0.z + w0.w * w0.w;
        s11 += w1.x * w1.x + w1.y * w1.y + w1.z * w1.z + w1.w * w1.w;
        s01 += w0.x * w1.x + w0.y * w1.y + w0.z * w1.z + w0.w * w1.w;
        // left rotation (row mix)
        const float a0x = cL * w0.x - sL * w1.x;
        const float a0y = cL * w0.y - sL * w1.y;
        const float a0z = cL * w0.z - sL * w1.z;
        const float a0w = cL * w0.w - sL * w1.w;
        const float a1x = sL * w0.x + cL * w1.x;
        const float a1y = sL * w0.y + cL * w1.y;
        const float a1z = sL * w0.z + cL * w1.z;
        const float a1w = sL * w0.w + cL * w1.w;
        // right rotation (col mix within (x,y) and (z,w))
        b0[k].x = cs.x * a0x - cs.y * a0y;
        b0[k].y = cs.y * a0x + cs.x * a0y;
        b0[k].z = cs.z * a0z - cs.w * a0w;
        b0[k].w = cs.w * a0z + cs.z * a0w;
        b1[k].x = cs.x * a1x - cs.y * a1y;
        b1[k].y = cs.y * a1x + cs.x * a1y;
        b1[k].z = cs.z * a1z - cs.w * a1w;
        b1[k].w = cs.w * a1z + cs.z * a1w;
    }

    // block reduction of 3 sums
#pragma unroll
    for (int off = 32; off; off >>= 1) {
        s00 += __shfl_down(s00, off);
        s11 += __shfl_down(s11, off);
        s01 += __shfl_down(s01, off);
    }
    __shared__ float red[3][4];
    __shared__ float scales[2];
    const int wave = tid >> 6, lane = tid & 63;
    if (lane == 0) { red[0][wave] = s00; red[1][wave] = s11; red[2][wave] = s01; }
    __syncthreads();
    if (tid == 0) {
        const float t0 = red[0][0] + red[0][1] + red[0][2] + red[0][3];
        const float t1 = red[1][0] + red[1][1] + red[1][2] + red[1][3];
        const float td = red[2][0] + red[2][1] + red[2][2] + red[2][3];
        // rotated row norms, analytic (right rotations preserve row norms)
        const float n0 = cL * cL * t0 + sL * sL * t1 - 2.f * cL * sL * td;
        const float n1 = sL * sL * t0 + cL * cL * t1 + 2.f * cL * sL * td;
        scales[0] = sqrtf(t0) * expf(ecd[i0]) / (sqrtf(n0) + 1e-8f);
        scales[1] = sqrtf(t1) * expf(ecd[i1]) / (sqrtf(n1) + 1e-8f);
    }
    __syncthreads();
    const float sc0 = scales[0], sc1 = scales[1];

    uint2* o0 = (uint2*)(Weff + (size_t)i0 * GK);   // 4 bf16 = 8B per float4
    uint2* o1 = (uint2*)(Weff + (size_t)i1 * GK);
#pragma unroll
    for (int k = 0; k < 4; k++) {
        const int c4 = tid + k * 256;
        uint2 p0, p1;
        p0.x = pack2bf(b0[k].x * sc0, b0[k].y * sc0);
        p0.y = pack2bf(b0[k].z * sc0, b0[k].w * sc0);
        p1.x = pack2bf(b1[k].x * sc1, b1[k].y * sc1);
        p1.y = pack2bf(b1[k].z * sc1, b1[k].w * sc1);
        o0[c4] = p0;
        o1[c4] = p1;
    }
}

// ---------------- GEMM  out = Xbf @ Weff^T + bias ----------------
// m97 structure: 128x128 tile, BK=32, 4 waves in 2x2, 4x4 mfma_16x16x32_bf16
// per wave, global_load_lds width=16 staging, 2-barrier K-loop. (unchanged)
static __device__ __forceinline__ void glds16(const unsigned short* g, unsigned short* l) {
    __builtin_amdgcn_global_load_lds(
        (const __attribute__((address_space(1))) unsigned int*)g,
        (__attribute__((address_space(3))) unsigned int*)l, 16, 0, 0);
}

__global__ __launch_bounds__(256) void gemm_bt(
    const unsigned short* __restrict__ A,   // (GT, GK) bf16
    const unsigned short* __restrict__ B,   // (GN, GK) bf16
    const float* __restrict__ bias,
    float* __restrict__ C)                  // (GT, GN) f32
{
    constexpr int BM = 128, BN = 128, BK = 32;
    __shared__ unsigned short As[BM * BK];
    __shared__ unsigned short Bs[BN * BK];

    const int tid  = threadIdx.x;
    const int lane = tid & 63;
    const int wave = tid >> 6;
    const int quad = lane >> 4;
    const int l16  = lane & 15;
    const int wm   = wave >> 1;     // 0..1
    const int wn   = wave & 1;      // 0..1
    const int bm   = blockIdx.y * BM;
    const int bn   = blockIdx.x * BN;

    const int srow = wave * 32 + (lane >> 2);   // tile row
    const int scol = (lane & 3) * 8;            // k within BK, bf16 units
    const unsigned short* gA0 = A + (size_t)(bm + srow) * GK + scol;
    const unsigned short* gA1 = A + (size_t)(bm + srow + 16) * GK + scol;
    const unsigned short* gB0 = B + (size_t)(bn + srow) * GK + scol;
    const unsigned short* gB1 = B + (size_t)(bn + srow + 16) * GK + scol;
    unsigned short* lA0 = &As[srow * BK + scol];
    unsigned short* lA1 = &As[(srow + 16) * BK + scol];
    unsigned short* lB0 = &Bs[srow * BK + scol];
    unsigned short* lB1 = &Bs[(srow + 16) * BK + scol];

    f32x4 acc[4][4] = {};

    for (int k0 = 0; k0 < GK; k0 += BK) {
        __syncthreads();                 // LDS reuse guard
        glds16(gA0 + k0, lA0);
        glds16(gA1 + k0, lA1);
        glds16(gB0 + k0, lB0);
        glds16(gB1 + k0, lB1);
        __syncthreads();                 // drains vmcnt before reads

        bf16x8 aF[4], bF[4];
#pragma unroll
        for (int i = 0; i < 4; i++)
            aF[i] = *(const bf16x8*)&As[(wm * 64 + i * 16 + l16) * BK + quad * 8];
#pragma unroll
        for (int j = 0; j < 4; j++)
            bF[j] = *(const bf16x8*)&Bs[(wn * 64 + j * 16 + l16) * BK + quad * 8];
#pragma unroll
        for (int i = 0; i < 4; i++)
#pragma unroll
            for (int j = 0; j < 4; j++)
                acc[i][j] = __builtin_amdgcn_mfma_f32_16x16x32_bf16(
                    aF[i], bF[j], acc[i][j], 0, 0, 0);
    }

    // epilogue: C/D layout col=lane&15, row=quad*4+reg   (m89/m91 verified)
#pragma unroll
    for (int i = 0; i < 4; i++) {
        const int m = bm + wm * 64 + i * 16 + quad * 4;
#pragma unroll
        for (int j = 0; j < 4; j++) {
            const int n = bn + wn * 64 + j * 16 + l16;
            const float bv = bias[n];
#pragma unroll
            for (int r = 0; r < 4; r++)
                C[(size_t)(m + r) * GN + n] = acc[i][j][r] + bv;
        }
    }
}

extern "C" void kernel_launch(void* const* d_in, const int* in_sizes, int n_in,
                              void* d_out, int out_size, void* d_ws, size_t ws_size,
                              hipStream_t stream) {
    const float* x    = (const float*)d_in[0];
    const float* W    = (const float*)d_in[1];
    const float* bias = (const float*)d_in[2];
    const float* thL  = (const float*)d_in[3];
    const float* thR  = (const float*)d_in[4];
    const float* ecd  = (const float*)d_in[5];
    // pairs_L / pairs_R (d_in[6], d_in[7]) are fixed arange reshapes:
    // pair s = (2s, 2s+1) — exploited structurally above.

    unsigned short* Weff = (unsigned short*)d_ws;                                // 32 MB
    unsigned short* Xbf  = (unsigned short*)((char*)d_ws + (size_t)GN * GK * 2); // 16 MB
    float2* csR = (float2*)((char*)d_ws + (size_t)GN * GK * 2 + (size_t)GT * GK * 2); // 16 KB

    float* out = (float*)d_out;

    sincos_pre<<<dim3(NPAIR / 256), dim3(256), 0, stream>>>(thR, csR);
    prelude<<<dim3(4096), dim3(256), 0, stream>>>(W, thL, csR, ecd, x, Weff, Xbf);
    gemm_bt<<<dim3(GN / 128, GT / 128), dim3(256), 0, stream>>>(Xbf, Weff, bias, out);
}